// Round 4
// baseline (168.362 us; speedup 1.0000x reference)
//
#include <hip/hip_runtime.h>
#include <math.h>

// StableSinkhornKnopp: B=16384 x K=1024 fp32, 3 iterations.
// Persistent kernel: E' = bf16(exp((x-M')*20)) lives ENTIRELY in LDS (each of
// 256 blocks owns a 64x1024 tile = 128 KiB). HBM traffic: x read + out write
// + ~0.5 MiB accumulator folds. 3 grid barriers (R0/R1/R2 global row-sums).
// Round-4 changes vs round-3 (k_sink ~59us, ~25us still coordination):
//  * TREE barrier arrival: 256 blocks fetch_add'ing ONE LLC line = ~256
//    serialized RMWs (~3-4us/barrier). Now 8 group counters (64-float apart,
//    32 arrivals each) + 8-wide root -> ~1us/barrier. Polls stay RELAXED sc1
//    (round-3 lesson: ACQUIRE polls = buffer_inv storm); all cross-block data
//    is read via sc1 relaxed loads, so no acquire fence is needed.
//  * k_zero launch removed: k_smax blocks write per-block maxes into 256
//    private slots (always fully overwritten -> no init needed) and zero the
//    P accumulators + barrier words themselves. k_sink reduces the 256 slots
//    per-wave (1 float4 load + 6 shfls, no extra sync).
//  * NONTEMPORAL final stores: out is never re-read on device; write-allocate
//    of 64 MiB was evicting x from the 256 MiB LLC between graph replays
//    (FETCH 33 MB despite x being only 64 MiB and read-only). nt stores keep
//    x LLC-resident -> phase B reads mostly from LLC.
//  * NSPREAD 8->16: halves per-line serialization of the partial atomicAdds.

typedef float f32x4 __attribute__((ext_vector_type(4)));

namespace {
constexpr int B_ROWS = 16384;
constexpr int K_COLS = 1024;
constexpr float INV_EPS = 20.0f;   // 1/0.05
constexpr float STAB = 1e-9f;
constexpr int NSPREAD = 16;
constexpr int NBLK = 256;
constexpr int RPB = 64;            // rows per block

// workspace float offsets
constexpr int OFF_MV   = 0;        // 256 per-block max slots (no init needed)
constexpr int OFF_BAR  = 256;      // cnt_g[8] @ +64*g, cnt_r @ +512, gen @ +576
constexpr int BAR_FLOATS = 640;    // [256, 896) zeroed by k_smax block 0
constexpr int OFF_P0   = 1024;                     // R0 parts 16x1024
constexpr int OFF_P1   = OFF_P0 + NSPREAD * 1024;  // R1 parts
constexpr int OFF_P2   = OFF_P1 + NSPREAD * 1024;  // R2 parts
constexpr int P_FLOATS = 3 * NSPREAD * 1024;       // 49152
constexpr int P_PER_BLK = P_FLOATS / NBLK;         // 192

// LDS byte offsets (dynamic)
constexpr unsigned L_E   = 0;                   // ushort E[64][1024] = 131072 B
constexpr unsigned L_SCR = 131072;              // float scr[4][1024] = 16384 B
constexpr unsigned L_R   = L_SCR + 16384;       // float r[1024]     = 4096 B
constexpr unsigned L_C   = L_R + 4096;          // float c[64]       = 256 B
constexpr unsigned L_RED = L_C + 256;           // float red[32]     = 128 B
constexpr unsigned LDS_BYTES = L_RED + 128;     // 151936 B (< 160 KiB)
}

__device__ inline unsigned bf16rne(float f) {   // round-to-nearest-even bf16 bits
  unsigned u = __float_as_uint(f);
  return (u + 0x7FFFu + ((u >> 16) & 1u)) >> 16;
}
__device__ inline float bf16tof(unsigned h) { return __uint_as_float(h << 16); }
__device__ inline float bf16lo(unsigned w) { return __uint_as_float(w << 16); }
__device__ inline float bf16hi(unsigned w) { return __uint_as_float(w & 0xFFFF0000u); }

// ---- sampled max + all workspace init (replaces k_zero) ----
__global__ void k_smax(const float4* __restrict__ x, float* __restrict__ ws) {
  __shared__ float sm[4];
  int t = threadIdx.x;  // 256
  int blk = blockIdx.x; // 256
  // zero this block's slice of the spread accumulators
  if (t < P_PER_BLK) ws[OFF_P0 + blk * P_PER_BLK + t] = 0.0f;
  // block 0 zeroes the barrier words (no one else touches them this kernel)
  if (blk == 0) {
    for (int i = t; i < BAR_FLOATS; i += 256) ws[OFF_BAR + i] = 0.0f;
  }
  const float4* xb = x + (size_t)blk * 16 * 1024;   // 16 KiB sample per 256 KiB
  float4 v0 = xb[t], v1 = xb[t + 256], v2 = xb[t + 512], v3 = xb[t + 768];
  float m = fmaxf(fmaxf(fmaxf(v0.x, v0.y), fmaxf(v0.z, v0.w)),
                  fmaxf(fmaxf(v1.x, v1.y), fmaxf(v1.z, v1.w)));
  m = fmaxf(m, fmaxf(fmaxf(fmaxf(v2.x, v2.y), fmaxf(v2.z, v2.w)),
                     fmaxf(fmaxf(v3.x, v3.y), fmaxf(v3.z, v3.w))));
  #pragma unroll
  for (int off = 32; off > 0; off >>= 1) m = fmaxf(m, __shfl_xor(m, off, 64));
  if ((t & 63) == 0) sm[t >> 6] = m;
  __syncthreads();
  if (t == 0) {
    m = fmaxf(fmaxf(sm[0], sm[1]), fmaxf(sm[2], sm[3]));
    ws[OFF_MV + blk] = m;    // private slot: no atomics, no init required
  }
}

// ---- tree grid barrier: 8 groups x 32 + root; RELAXED sc1 polls ----
__device__ inline void gbar(float* ws) {
  __syncthreads();
  if (threadIdx.x == 0) {
    unsigned* cnt_g = (unsigned*)(ws + OFF_BAR + 64 * (blockIdx.x >> 5));
    unsigned* cnt_r = (unsigned*)(ws + OFF_BAR + 512);
    unsigned* gen   = (unsigned*)(ws + OFF_BAR + 576);
    unsigned g = __hip_atomic_load(gen, __ATOMIC_RELAXED, __HIP_MEMORY_SCOPE_AGENT);
    // release-half orders this block's prior atomicAdds before the arrival
    unsigned a = __hip_atomic_fetch_add(cnt_g, 1u, __ATOMIC_ACQ_REL, __HIP_MEMORY_SCOPE_AGENT);
    bool last = false;
    if (a == 31u) {
      unsigned b = __hip_atomic_fetch_add(cnt_r, 1u, __ATOMIC_ACQ_REL, __HIP_MEMORY_SCOPE_AGENT);
      if (b == 7u) {
        // reset ALL counters BEFORE bumping gen (release store orders them)
        #pragma unroll
        for (int i = 0; i < 8; ++i)
          __hip_atomic_store((unsigned*)(ws + OFF_BAR + 64 * i), 0u,
                             __ATOMIC_RELAXED, __HIP_MEMORY_SCOPE_AGENT);
        __hip_atomic_store(cnt_r, 0u, __ATOMIC_RELAXED, __HIP_MEMORY_SCOPE_AGENT);
        __hip_atomic_store(gen, g + 1u, __ATOMIC_RELEASE, __HIP_MEMORY_SCOPE_AGENT);
        last = true;
      }
    }
    if (!last) {
      // RELAXED poll: reads the coherence point without L2 invalidates.
      while (__hip_atomic_load(gen, __ATOMIC_RELAXED, __HIP_MEMORY_SCOPE_AGENT) == g) {
        __builtin_amdgcn_s_sleep(2);
      }
    }
  }
  __syncthreads();
}

__global__ void __launch_bounds__(1024, 4)
k_sink(const float* __restrict__ x, float* __restrict__ out,
       float* __restrict__ ws) {
  extern __shared__ char lds_raw[];
  unsigned short* E = (unsigned short*)(lds_raw + L_E);
  float* scr = (float*)(lds_raw + L_SCR);
  float* r_l = (float*)(lds_raw + L_R);
  float* c_l = (float*)(lds_raw + L_C);
  float* red = (float*)(lds_raw + L_RED);

  const int t = threadIdx.x;       // 1024
  const int blk = blockIdx.x;      // 256
  const int lane = t & 63;
  const int wave = t >> 6;         // 0..15
  const int c0 = t & 255;          // col group: cols 4*c0 .. 4*c0+3
  const int r0 = t >> 8;           // row subgroup 0..3

  const float* xb = x + (size_t)blk * RPB * K_COLS;

  // ---- M: every wave redundantly reduces the 256 per-block max slots ----
  float M;
  {
    float4 q = *(const float4*)(ws + OFF_MV + 4 * lane);  // 64 lanes x 4 = 256
    float m = fmaxf(fmaxf(q.x, q.y), fmaxf(q.z, q.w));
    #pragma unroll
    for (int off = 32; off > 0; off >>= 1) m = fmaxf(m, __shfl_xor(m, off, 64));
    M = m;   // wave-uniform, no syncthreads needed
  }

  // ---- Phase B: E' = bf16(exp((x-M)*20)) -> LDS; R0 partials -> spread ----
  {
    float a0 = 0.f, a1 = 0.f, a2 = 0.f, a3 = 0.f;
    #pragma unroll 4
    for (int i = 0; i < 16; ++i) {
      const int row = 4 * i + r0;
      float4 v = *(const float4*)(xb + (size_t)row * K_COLS + 4 * c0);
      unsigned h0 = bf16rne(__expf((v.x - M) * INV_EPS));
      unsigned h1 = bf16rne(__expf((v.y - M) * INV_EPS));
      unsigned h2 = bf16rne(__expf((v.z - M) * INV_EPS));
      unsigned h3 = bf16rne(__expf((v.w - M) * INV_EPS));
      ushort4 hs;
      hs.x = (unsigned short)h0; hs.y = (unsigned short)h1;
      hs.z = (unsigned short)h2; hs.w = (unsigned short)h3;
      *(ushort4*)(E + row * K_COLS + 4 * c0) = hs;
      // accumulate the QUANTIZED values so all passes agree exactly
      a0 += bf16tof(h0); a1 += bf16tof(h1); a2 += bf16tof(h2); a3 += bf16tof(h3);
    }
    float4 f4; f4.x = a0; f4.y = a1; f4.z = a2; f4.w = a3;
    *(float4*)(scr + r0 * 1024 + 4 * c0) = f4;
    __syncthreads();
    float cs = scr[t] + scr[1024 + t] + scr[2048 + t] + scr[3072 + t];
    atomicAdd(ws + OFF_P0 + (blk & (NSPREAD - 1)) * 1024 + t, cs);
  }
  gbar(ws);

  // ---- fold R0 with sc1 loads (bypass non-coherent L2), S, s, r1, c=1 ----
  float s;
  {
    float R0t = 0.f;
    #pragma unroll
    for (int i = 0; i < NSPREAD; ++i)
      R0t += __hip_atomic_load(ws + OFF_P0 + i * 1024 + t,
                               __ATOMIC_RELAXED, __HIP_MEMORY_SCOPE_AGENT);
    float p = R0t;
    #pragma unroll
    for (int off = 32; off > 0; off >>= 1) p += __shfl_xor(p, off, 64);
    if (lane == 0) red[wave] = p;
    __syncthreads();
    float S = 0.f;
    #pragma unroll
    for (int i = 0; i < 16; ++i) S += red[i];   // same order in every block/thread
    s = 1.0f / (S + STAB);
    r_l[t] = 1.0f / ((s * R0t + STAB) * K_COLS);
    if (t < 64) c_l[t] = 1.0f;
    __syncthreads();
  }

  // ---- column-normalize: c_new[b] from p[b] = sum_k E'[b,k]*r[k] ----
  float rv[16];
  auto load_rv = [&]() {
    #pragma unroll
    for (int j = 0; j < 4; ++j) {
      float4 rr = *(const float4*)(r_l + 256 * j + 4 * lane);
      rv[4 * j + 0] = rr.x; rv[4 * j + 1] = rr.y;
      rv[4 * j + 2] = rr.z; rv[4 * j + 3] = rr.w;
    }
  };

  auto col_pass = [&](bool first) {
    load_rv();
    #pragma unroll
    for (int half = 0; half < 2; ++half) {
      const int row0 = wave + 32 * half;   // wave handles rows {w, w+16, w+32, w+48}
      const int row1 = row0 + 16;
      const unsigned short* e0p = E + row0 * K_COLS + 4 * lane;
      const unsigned short* e1p = E + row1 * K_COLS + 4 * lane;
      float p0 = 0.f, p1 = 0.f;
      #pragma unroll
      for (int j = 0; j < 4; ++j) {
        uint2 u = *(const uint2*)(e0p + 256 * j);
        uint2 v = *(const uint2*)(e1p + 256 * j);
        p0 += bf16lo(u.x) * rv[4*j+0] + bf16hi(u.x) * rv[4*j+1]
            + bf16lo(u.y) * rv[4*j+2] + bf16hi(u.y) * rv[4*j+3];
        p1 += bf16lo(v.x) * rv[4*j+0] + bf16hi(v.x) * rv[4*j+1]
            + bf16lo(v.y) * rv[4*j+2] + bf16hi(v.y) * rv[4*j+3];
      }
      #pragma unroll
      for (int off = 32; off > 0; off >>= 1) {
        p0 += __shfl_xor(p0, off, 64);
        p1 += __shfl_xor(p1, off, 64);
      }
      if (lane == 0) {
        float ci0 = first ? 1.0f : c_l[row0];
        float ci1 = first ? 1.0f : c_l[row1];
        c_l[row0] = ci0 / ((s * ci0 * p0 + STAB) * B_ROWS);
        c_l[row1] = ci1 / ((s * ci1 * p1 + STAB) * B_ROWS);
      }
    }
    __syncthreads();
  };

  // ---- next row-sum partials: A[k] = sum_b E'[b,k]*c[b] -> spread atomics ----
  auto col_acc = [&](float* part) {
    float a0 = 0.f, a1 = 0.f, a2 = 0.f, a3 = 0.f;
    const unsigned short* ep = E + (size_t)(16 * r0) * K_COLS + 4 * c0;
    const float* cp = c_l + 16 * r0;
    #pragma unroll 4
    for (int rr = 0; rr < 16; ++rr) {
      float cv = cp[rr];                       // wave-uniform -> LDS broadcast
      uint2 u = *(const uint2*)(ep + rr * K_COLS);
      a0 += bf16lo(u.x) * cv; a1 += bf16hi(u.x) * cv;
      a2 += bf16lo(u.y) * cv; a3 += bf16hi(u.y) * cv;
    }
    float4 f4; f4.x = a0; f4.y = a1; f4.z = a2; f4.w = a3;
    *(float4*)(scr + r0 * 1024 + 4 * c0) = f4;
    __syncthreads();
    float A = scr[t] + scr[1024 + t] + scr[2048 + t] + scr[3072 + t];
    atomicAdd(part + (blk & (NSPREAD - 1)) * 1024 + t, A);
  };

  // ---- r_new[k] = r[k]/((s*r[k]*A[k]+eps)*K), folding spread parts (sc1) ----
  auto upd_r = [&](float* part) {
    float A = 0.f;
    #pragma unroll
    for (int i = 0; i < NSPREAD; ++i)
      A += __hip_atomic_load(part + i * 1024 + t,
                             __ATOMIC_RELAXED, __HIP_MEMORY_SCOPE_AGENT);
    float rvv = r_l[t];
    r_l[t] = rvv / ((s * rvv * A + STAB) * K_COLS);
    __syncthreads();
  };

  float* P1 = ws + OFF_P1;
  float* P2 = ws + OFF_P2;

  col_pass(true);        // c1
  col_acc(P1);           // R1 parts
  gbar(ws);
  upd_r(P1);             // r2
  col_pass(false);       // c2
  col_acc(P2);           // R2 parts
  gbar(ws);
  upd_r(P2);             // r3

  // ---- fused: c3 + output write. Butterfly leaves p in ALL lanes, so every
  //      lane knows c3; E fragments + rv are already in registers -> write
  //      out = s*E'*r3*c3*B directly with NONTEMPORAL stores (out is never
  //      re-read on device; avoid evicting x from LLC via write-allocate). ----
  {
    load_rv();           // r3
    #pragma unroll
    for (int half = 0; half < 2; ++half) {
      const int row0 = wave + 32 * half;
      const int row1 = row0 + 16;
      const unsigned short* e0p = E + row0 * K_COLS + 4 * lane;
      const unsigned short* e1p = E + row1 * K_COLS + 4 * lane;
      float q0[16], q1[16];
      #pragma unroll
      for (int j = 0; j < 4; ++j) {
        uint2 u = *(const uint2*)(e0p + 256 * j);
        uint2 v = *(const uint2*)(e1p + 256 * j);
        q0[4*j+0] = bf16lo(u.x) * rv[4*j+0];
        q0[4*j+1] = bf16hi(u.x) * rv[4*j+1];
        q0[4*j+2] = bf16lo(u.y) * rv[4*j+2];
        q0[4*j+3] = bf16hi(u.y) * rv[4*j+3];
        q1[4*j+0] = bf16lo(v.x) * rv[4*j+0];
        q1[4*j+1] = bf16hi(v.x) * rv[4*j+1];
        q1[4*j+2] = bf16lo(v.y) * rv[4*j+2];
        q1[4*j+3] = bf16hi(v.y) * rv[4*j+3];
      }
      float p0 = 0.f, p1 = 0.f;
      #pragma unroll
      for (int i = 0; i < 16; ++i) { p0 += q0[i]; p1 += q1[i]; }
      #pragma unroll
      for (int off = 32; off > 0; off >>= 1) {
        p0 += __shfl_xor(p0, off, 64);
        p1 += __shfl_xor(p1, off, 64);
      }
      float ci0 = c_l[row0];                   // wave-uniform LDS broadcast
      float ci1 = c_l[row1];
      float c0n = ci0 / ((s * ci0 * p0 + STAB) * B_ROWS);
      float c1n = ci1 / ((s * ci1 * p1 + STAB) * B_ROWS);
      float f0 = s * c0n * (float)B_ROWS;
      float f1 = s * c1n * (float)B_ROWS;
      float* o0 = out + (size_t)(blk * RPB + row0) * K_COLS + 4 * lane;
      float* o1 = out + (size_t)(blk * RPB + row1) * K_COLS + 4 * lane;
      #pragma unroll
      for (int j = 0; j < 4; ++j) {
        f32x4 a, b;
        a.x = q0[4*j+0] * f0; a.y = q0[4*j+1] * f0;
        a.z = q0[4*j+2] * f0; a.w = q0[4*j+3] * f0;
        b.x = q1[4*j+0] * f1; b.y = q1[4*j+1] * f1;
        b.z = q1[4*j+2] * f1; b.w = q1[4*j+3] * f1;
        __builtin_nontemporal_store(a, (f32x4*)(o0 + 256 * j));
        __builtin_nontemporal_store(b, (f32x4*)(o1 + 256 * j));
      }
    }
  }
}

extern "C" void kernel_launch(void* const* d_in, const int* in_sizes, int n_in,
                              void* d_out, int out_size, void* d_ws, size_t ws_size,
                              hipStream_t stream) {
  const float* x = (const float*)d_in[0];
  float* out = (float*)d_out;
  float* ws = (float*)d_ws;
  (void)in_sizes; (void)n_in; (void)out_size; (void)ws_size;

  static bool attr_set = false;
  if (!attr_set) {
    // opt-in for >64 KiB dynamic LDS
    hipFuncSetAttribute((const void*)k_sink,
                        hipFuncAttributeMaxDynamicSharedMemorySize,
                        (int)LDS_BYTES);
    attr_set = true;
  }

  k_smax<<<256, 256, 0, stream>>>((const float4*)x, ws);  // max slots + init
  void* args[] = {(void*)&x, (void*)&out, (void*)&ws};
  // cooperative launch solely for the co-residency guarantee (256 blocks = 256 CUs)
  hipLaunchCooperativeKernel((void*)k_sink, dim3(NBLK), dim3(1024),
                             args, LDS_BYTES, stream);
}

// Round 5
// 163.868 us; speedup vs baseline: 1.0274x; 1.0274x over previous
//
#include <hip/hip_runtime.h>
#include <math.h>

// StableSinkhornKnopp: B=16384 x K=1024 fp32, 3 iterations.
// Persistent kernel: E' = bf16(exp((x-M')*20)) lives ENTIRELY in LDS (each of
// 256 blocks owns a 64x1024 tile = 128 KiB). HBM traffic: x read + out write
// + ~0.3 MiB accumulator folds. 3 grid barriers (R0/R1/R2 global row-sums).
//
// Round-5 = controlled unbundle of round-4's +13us regression:
//  * REVERTED to round-3 proven paths: regular float4 final stores (nt stores
//    bypassed L2 write-combining for zero benefit -- FETCH didn't drop, the
//    LLC evictor is the harness's 268MB ws re-poison, not out-writes) and
//    NSPREAD=8 (16 doubled fold traffic).
//  * KEPT from round-4 (theoretically sound, now isolated): tree barrier
//    (8 group counters on separate lines + 8-wide root, RELAXED sc1 polls
//    with s_sleep(4) -- round-3 lesson: ACQUIRE polls = buffer_inv storm),
//    and k_zero elimination (k_smax writes per-block maxes to 256 private
//    slots needing no init, zeroes P accumulators + barrier words).
//  * All cross-block data after a barrier (P0/P1/P2, written by device-scope
//    atomicAdd at the coherence point) is folded with sc1 RELAXED atomic
//    loads bypassing the non-coherent per-XCD L2 -> no acquire fence needed.

namespace {
constexpr int B_ROWS = 16384;
constexpr int K_COLS = 1024;
constexpr float INV_EPS = 20.0f;   // 1/0.05
constexpr float STAB = 1e-9f;
constexpr int NSPREAD = 8;
constexpr int NBLK = 256;
constexpr int RPB = 64;            // rows per block

// workspace float offsets
constexpr int OFF_MV   = 0;        // 256 per-block max slots (no init needed)
constexpr int OFF_BAR  = 256;      // cnt_g[8] @ +64*g, cnt_r @ +512, gen @ +576
constexpr int BAR_FLOATS = 640;    // [256, 896) zeroed by k_smax block 0
constexpr int OFF_P0   = 1024;                     // R0 parts 8x1024
constexpr int OFF_P1   = OFF_P0 + NSPREAD * 1024;  // R1 parts
constexpr int OFF_P2   = OFF_P1 + NSPREAD * 1024;  // R2 parts
constexpr int P_FLOATS = 3 * NSPREAD * 1024;       // 24576
constexpr int P_PER_BLK = P_FLOATS / NBLK;         // 96

// LDS byte offsets (dynamic)
constexpr unsigned L_E   = 0;                   // ushort E[64][1024] = 131072 B
constexpr unsigned L_SCR = 131072;              // float scr[4][1024] = 16384 B
constexpr unsigned L_R   = L_SCR + 16384;       // float r[1024]     = 4096 B
constexpr unsigned L_C   = L_R + 4096;          // float c[64]       = 256 B
constexpr unsigned L_RED = L_C + 256;           // float red[32]     = 128 B
constexpr unsigned LDS_BYTES = L_RED + 128;     // 151936 B (< 160 KiB)
}

__device__ inline unsigned bf16rne(float f) {   // round-to-nearest-even bf16 bits
  unsigned u = __float_as_uint(f);
  return (u + 0x7FFFu + ((u >> 16) & 1u)) >> 16;
}
__device__ inline float bf16tof(unsigned h) { return __uint_as_float(h << 16); }
__device__ inline float bf16lo(unsigned w) { return __uint_as_float(w << 16); }
__device__ inline float bf16hi(unsigned w) { return __uint_as_float(w & 0xFFFF0000u); }

// ---- sampled max + all workspace init (replaces k_zero) ----
__global__ void k_smax(const float4* __restrict__ x, float* __restrict__ ws) {
  __shared__ float sm[4];
  int t = threadIdx.x;  // 256
  int blk = blockIdx.x; // 256
  // zero this block's slice of the spread accumulators
  if (t < P_PER_BLK) ws[OFF_P0 + blk * P_PER_BLK + t] = 0.0f;
  // block 0 zeroes the barrier words (no one else touches them this kernel)
  if (blk == 0) {
    for (int i = t; i < BAR_FLOATS; i += 256) ws[OFF_BAR + i] = 0.0f;
  }
  const float4* xb = x + (size_t)blk * 16 * 1024;   // 16 KiB sample per 256 KiB
  float4 v0 = xb[t], v1 = xb[t + 256], v2 = xb[t + 512], v3 = xb[t + 768];
  float m = fmaxf(fmaxf(fmaxf(v0.x, v0.y), fmaxf(v0.z, v0.w)),
                  fmaxf(fmaxf(v1.x, v1.y), fmaxf(v1.z, v1.w)));
  m = fmaxf(m, fmaxf(fmaxf(fmaxf(v2.x, v2.y), fmaxf(v2.z, v2.w)),
                     fmaxf(fmaxf(v3.x, v3.y), fmaxf(v3.z, v3.w))));
  #pragma unroll
  for (int off = 32; off > 0; off >>= 1) m = fmaxf(m, __shfl_xor(m, off, 64));
  if ((t & 63) == 0) sm[t >> 6] = m;
  __syncthreads();
  if (t == 0) {
    m = fmaxf(fmaxf(sm[0], sm[1]), fmaxf(sm[2], sm[3]));
    ws[OFF_MV + blk] = m;    // private slot: no atomics, no init required
  }
}

// ---- tree grid barrier: 8 groups x 32 + root; RELAXED sc1 polls ----
__device__ inline void gbar(float* ws) {
  __syncthreads();
  if (threadIdx.x == 0) {
    unsigned* cnt_g = (unsigned*)(ws + OFF_BAR + 64 * (blockIdx.x >> 5));
    unsigned* cnt_r = (unsigned*)(ws + OFF_BAR + 512);
    unsigned* gen   = (unsigned*)(ws + OFF_BAR + 576);
    unsigned g = __hip_atomic_load(gen, __ATOMIC_RELAXED, __HIP_MEMORY_SCOPE_AGENT);
    // release-half orders this block's prior atomicAdds before the arrival
    unsigned a = __hip_atomic_fetch_add(cnt_g, 1u, __ATOMIC_ACQ_REL, __HIP_MEMORY_SCOPE_AGENT);
    bool last = false;
    if (a == 31u) {
      unsigned b = __hip_atomic_fetch_add(cnt_r, 1u, __ATOMIC_ACQ_REL, __HIP_MEMORY_SCOPE_AGENT);
      if (b == 7u) {
        // reset ALL counters BEFORE bumping gen; the RELEASE store on gen
        // waits vmcnt(0) so resets are globally complete before gen flips
        #pragma unroll
        for (int i = 0; i < 8; ++i)
          __hip_atomic_store((unsigned*)(ws + OFF_BAR + 64 * i), 0u,
                             __ATOMIC_RELAXED, __HIP_MEMORY_SCOPE_AGENT);
        __hip_atomic_store(cnt_r, 0u, __ATOMIC_RELAXED, __HIP_MEMORY_SCOPE_AGENT);
        __hip_atomic_store(gen, g + 1u, __ATOMIC_RELEASE, __HIP_MEMORY_SCOPE_AGENT);
        last = true;
      }
    }
    if (!last) {
      // RELAXED poll: reads the coherence point without L2 invalidates.
      while (__hip_atomic_load(gen, __ATOMIC_RELAXED, __HIP_MEMORY_SCOPE_AGENT) == g) {
        __builtin_amdgcn_s_sleep(4);
      }
    }
  }
  __syncthreads();
}

__global__ void __launch_bounds__(1024, 4)
k_sink(const float* __restrict__ x, float* __restrict__ out,
       float* __restrict__ ws) {
  extern __shared__ char lds_raw[];
  unsigned short* E = (unsigned short*)(lds_raw + L_E);
  float* scr = (float*)(lds_raw + L_SCR);
  float* r_l = (float*)(lds_raw + L_R);
  float* c_l = (float*)(lds_raw + L_C);
  float* red = (float*)(lds_raw + L_RED);

  const int t = threadIdx.x;       // 1024
  const int blk = blockIdx.x;      // 256
  const int lane = t & 63;
  const int wave = t >> 6;         // 0..15
  const int c0 = t & 255;          // col group: cols 4*c0 .. 4*c0+3
  const int r0 = t >> 8;           // row subgroup 0..3

  const float* xb = x + (size_t)blk * RPB * K_COLS;

  // ---- M: every wave redundantly reduces the 256 per-block max slots ----
  float M;
  {
    float4 q = *(const float4*)(ws + OFF_MV + 4 * lane);  // 64 lanes x 4 = 256
    float m = fmaxf(fmaxf(q.x, q.y), fmaxf(q.z, q.w));
    #pragma unroll
    for (int off = 32; off > 0; off >>= 1) m = fmaxf(m, __shfl_xor(m, off, 64));
    M = m;   // wave-uniform, no syncthreads needed
  }

  // ---- Phase B: E' = bf16(exp((x-M)*20)) -> LDS; R0 partials -> spread ----
  {
    float a0 = 0.f, a1 = 0.f, a2 = 0.f, a3 = 0.f;
    #pragma unroll 4
    for (int i = 0; i < 16; ++i) {
      const int row = 4 * i + r0;
      float4 v = *(const float4*)(xb + (size_t)row * K_COLS + 4 * c0);
      unsigned h0 = bf16rne(__expf((v.x - M) * INV_EPS));
      unsigned h1 = bf16rne(__expf((v.y - M) * INV_EPS));
      unsigned h2 = bf16rne(__expf((v.z - M) * INV_EPS));
      unsigned h3 = bf16rne(__expf((v.w - M) * INV_EPS));
      ushort4 hs;
      hs.x = (unsigned short)h0; hs.y = (unsigned short)h1;
      hs.z = (unsigned short)h2; hs.w = (unsigned short)h3;
      *(ushort4*)(E + row * K_COLS + 4 * c0) = hs;
      // accumulate the QUANTIZED values so all passes agree exactly
      a0 += bf16tof(h0); a1 += bf16tof(h1); a2 += bf16tof(h2); a3 += bf16tof(h3);
    }
    float4 f4; f4.x = a0; f4.y = a1; f4.z = a2; f4.w = a3;
    *(float4*)(scr + r0 * 1024 + 4 * c0) = f4;
    __syncthreads();
    float cs = scr[t] + scr[1024 + t] + scr[2048 + t] + scr[3072 + t];
    atomicAdd(ws + OFF_P0 + (blk & (NSPREAD - 1)) * 1024 + t, cs);
  }
  gbar(ws);

  // ---- fold R0 with sc1 loads (bypass non-coherent L2), S, s, r1, c=1 ----
  float s;
  {
    float R0t = 0.f;
    #pragma unroll
    for (int i = 0; i < NSPREAD; ++i)
      R0t += __hip_atomic_load(ws + OFF_P0 + i * 1024 + t,
                               __ATOMIC_RELAXED, __HIP_MEMORY_SCOPE_AGENT);
    float p = R0t;
    #pragma unroll
    for (int off = 32; off > 0; off >>= 1) p += __shfl_xor(p, off, 64);
    if (lane == 0) red[wave] = p;
    __syncthreads();
    float S = 0.f;
    #pragma unroll
    for (int i = 0; i < 16; ++i) S += red[i];   // same order in every block/thread
    s = 1.0f / (S + STAB);
    r_l[t] = 1.0f / ((s * R0t + STAB) * K_COLS);
    if (t < 64) c_l[t] = 1.0f;
    __syncthreads();
  }

  // ---- column-normalize: c_new[b] from p[b] = sum_k E'[b,k]*r[k] ----
  float rv[16];
  auto load_rv = [&]() {
    #pragma unroll
    for (int j = 0; j < 4; ++j) {
      float4 rr = *(const float4*)(r_l + 256 * j + 4 * lane);
      rv[4 * j + 0] = rr.x; rv[4 * j + 1] = rr.y;
      rv[4 * j + 2] = rr.z; rv[4 * j + 3] = rr.w;
    }
  };

  auto col_pass = [&](bool first) {
    load_rv();
    #pragma unroll
    for (int half = 0; half < 2; ++half) {
      const int row0 = wave + 32 * half;   // wave handles rows {w, w+16, w+32, w+48}
      const int row1 = row0 + 16;
      const unsigned short* e0p = E + row0 * K_COLS + 4 * lane;
      const unsigned short* e1p = E + row1 * K_COLS + 4 * lane;
      float p0 = 0.f, p1 = 0.f;
      #pragma unroll
      for (int j = 0; j < 4; ++j) {
        uint2 u = *(const uint2*)(e0p + 256 * j);
        uint2 v = *(const uint2*)(e1p + 256 * j);
        p0 += bf16lo(u.x) * rv[4*j+0] + bf16hi(u.x) * rv[4*j+1]
            + bf16lo(u.y) * rv[4*j+2] + bf16hi(u.y) * rv[4*j+3];
        p1 += bf16lo(v.x) * rv[4*j+0] + bf16hi(v.x) * rv[4*j+1]
            + bf16lo(v.y) * rv[4*j+2] + bf16hi(v.y) * rv[4*j+3];
      }
      #pragma unroll
      for (int off = 32; off > 0; off >>= 1) {
        p0 += __shfl_xor(p0, off, 64);
        p1 += __shfl_xor(p1, off, 64);
      }
      if (lane == 0) {
        float ci0 = first ? 1.0f : c_l[row0];
        float ci1 = first ? 1.0f : c_l[row1];
        c_l[row0] = ci0 / ((s * ci0 * p0 + STAB) * B_ROWS);
        c_l[row1] = ci1 / ((s * ci1 * p1 + STAB) * B_ROWS);
      }
    }
    __syncthreads();
  };

  // ---- next row-sum partials: A[k] = sum_b E'[b,k]*c[b] -> spread atomics ----
  auto col_acc = [&](float* part) {
    float a0 = 0.f, a1 = 0.f, a2 = 0.f, a3 = 0.f;
    const unsigned short* ep = E + (size_t)(16 * r0) * K_COLS + 4 * c0;
    const float* cp = c_l + 16 * r0;
    #pragma unroll 4
    for (int rr = 0; rr < 16; ++rr) {
      float cv = cp[rr];                       // wave-uniform -> LDS broadcast
      uint2 u = *(const uint2*)(ep + rr * K_COLS);
      a0 += bf16lo(u.x) * cv; a1 += bf16hi(u.x) * cv;
      a2 += bf16lo(u.y) * cv; a3 += bf16hi(u.y) * cv;
    }
    float4 f4; f4.x = a0; f4.y = a1; f4.z = a2; f4.w = a3;
    *(float4*)(scr + r0 * 1024 + 4 * c0) = f4;
    __syncthreads();
    float A = scr[t] + scr[1024 + t] + scr[2048 + t] + scr[3072 + t];
    atomicAdd(part + (blk & (NSPREAD - 1)) * 1024 + t, A);
  };

  // ---- r_new[k] = r[k]/((s*r[k]*A[k]+eps)*K), folding spread parts (sc1) ----
  auto upd_r = [&](float* part) {
    float A = 0.f;
    #pragma unroll
    for (int i = 0; i < NSPREAD; ++i)
      A += __hip_atomic_load(part + i * 1024 + t,
                             __ATOMIC_RELAXED, __HIP_MEMORY_SCOPE_AGENT);
    float rvv = r_l[t];
    r_l[t] = rvv / ((s * rvv * A + STAB) * K_COLS);
    __syncthreads();
  };

  float* P1 = ws + OFF_P1;
  float* P2 = ws + OFF_P2;

  col_pass(true);        // c1
  col_acc(P1);           // R1 parts
  gbar(ws);
  upd_r(P1);             // r2
  col_pass(false);       // c2
  col_acc(P2);           // R2 parts
  gbar(ws);
  upd_r(P2);             // r3

  // ---- fused: c3 + output write. Butterfly leaves p in ALL lanes, so every
  //      lane knows c3; E fragments + rv are already in registers -> write
  //      out[row,k] = s * E' * r3[k] * c3[row] * B directly (regular float4
  //      stores -- round-4's nt stores regressed). ----
  {
    load_rv();           // r3
    #pragma unroll
    for (int half = 0; half < 2; ++half) {
      const int row0 = wave + 32 * half;
      const int row1 = row0 + 16;
      const unsigned short* e0p = E + row0 * K_COLS + 4 * lane;
      const unsigned short* e1p = E + row1 * K_COLS + 4 * lane;
      float q0[16], q1[16];
      #pragma unroll
      for (int j = 0; j < 4; ++j) {
        uint2 u = *(const uint2*)(e0p + 256 * j);
        uint2 v = *(const uint2*)(e1p + 256 * j);
        q0[4*j+0] = bf16lo(u.x) * rv[4*j+0];
        q0[4*j+1] = bf16hi(u.x) * rv[4*j+1];
        q0[4*j+2] = bf16lo(u.y) * rv[4*j+2];
        q0[4*j+3] = bf16hi(u.y) * rv[4*j+3];
        q1[4*j+0] = bf16lo(v.x) * rv[4*j+0];
        q1[4*j+1] = bf16hi(v.x) * rv[4*j+1];
        q1[4*j+2] = bf16lo(v.y) * rv[4*j+2];
        q1[4*j+3] = bf16hi(v.y) * rv[4*j+3];
      }
      float p0 = 0.f, p1 = 0.f;
      #pragma unroll
      for (int i = 0; i < 16; ++i) { p0 += q0[i]; p1 += q1[i]; }
      #pragma unroll
      for (int off = 32; off > 0; off >>= 1) {
        p0 += __shfl_xor(p0, off, 64);
        p1 += __shfl_xor(p1, off, 64);
      }
      float ci0 = c_l[row0];                   // wave-uniform LDS broadcast
      float ci1 = c_l[row1];
      float c0n = ci0 / ((s * ci0 * p0 + STAB) * B_ROWS);
      float c1n = ci1 / ((s * ci1 * p1 + STAB) * B_ROWS);
      float f0 = s * c0n * (float)B_ROWS;
      float f1 = s * c1n * (float)B_ROWS;
      float* o0 = out + (size_t)(blk * RPB + row0) * K_COLS + 4 * lane;
      float* o1 = out + (size_t)(blk * RPB + row1) * K_COLS + 4 * lane;
      #pragma unroll
      for (int j = 0; j < 4; ++j) {
        float4 a, b;
        a.x = q0[4*j+0] * f0; a.y = q0[4*j+1] * f0;
        a.z = q0[4*j+2] * f0; a.w = q0[4*j+3] * f0;
        b.x = q1[4*j+0] * f1; b.y = q1[4*j+1] * f1;
        b.z = q1[4*j+2] * f1; b.w = q1[4*j+3] * f1;
        *(float4*)(o0 + 256 * j) = a;
        *(float4*)(o1 + 256 * j) = b;
      }
    }
  }
}

extern "C" void kernel_launch(void* const* d_in, const int* in_sizes, int n_in,
                              void* d_out, int out_size, void* d_ws, size_t ws_size,
                              hipStream_t stream) {
  const float* x = (const float*)d_in[0];
  float* out = (float*)d_out;
  float* ws = (float*)d_ws;
  (void)in_sizes; (void)n_in; (void)out_size; (void)ws_size;

  static bool attr_set = false;
  if (!attr_set) {
    // opt-in for >64 KiB dynamic LDS
    hipFuncSetAttribute((const void*)k_sink,
                        hipFuncAttributeMaxDynamicSharedMemorySize,
                        (int)LDS_BYTES);
    attr_set = true;
  }

  k_smax<<<256, 256, 0, stream>>>((const float4*)x, ws);  // max slots + init
  void* args[] = {(void*)&x, (void*)&out, (void*)&ws};
  // cooperative launch solely for the co-residency guarantee (256 blocks = 256 CUs)
  hipLaunchCooperativeKernel((void*)k_sink, dim3(NBLK), dim3(1024),
                             args, LDS_BYTES, stream);
}

// Round 6
// 141.594 us; speedup vs baseline: 1.1890x; 1.1573x over previous
//
#include <hip/hip_runtime.h>
#include <math.h>

// StableSinkhornKnopp: B=16384 x K=1024 fp32, 3 iterations.
// Persistent kernel: E' = bf16(exp((x-M')*20)) lives ENTIRELY in LDS (each of
// 256 blocks owns a 64x1024 tile = 128 KiB). HBM traffic: x read + out write
// + ~0.3 MiB accumulator folds. 3 grid barriers (R0/R1/R2 global row-sums).
//
// Round-6 = SINGLE change vs round-5: hipLaunchCooperativeKernel -> PLAIN
// launch. Dispatch-sum vs bench-total shows ~21us of graph-node gap over only
// 4 nodes (~5-7us/boundary vs round-0's ~1.8); the cooperative node is the
// outlier (extra validation + sync work per replay). Co-residency no longer
// needs the API: 256 blocks x 148KB LDS = exactly 1 block/CU on 256 CUs, so
// a plain launch is physically fully co-resident (5 rounds of cooperative
// validation passing proves device-wide capacity). The barrier is symmetric
// arrive+spin: dispatch-order independent, deadlock-free given co-residency.
//
// Carried structure (proven over rounds 2-5):
//  * RELAXED sc1 barrier polls (ACQUIRE polls = per-iteration buffer_inv
//    storm on the XCD L2s, +20us/barrier -- round-3 lesson).
//  * Cross-block data after a barrier (P0/P1/P2, written by device-scope
//    atomicAdd at the coherence point) folded with sc1 RELAXED atomic loads
//    bypassing the non-coherent per-XCD L2 -> no acquire fence needed.
//  * Tree barrier (neutral vs flat, kept), k_zero folded into k_smax,
//    regular float4 final stores (nt stores regressed), NSPREAD=8.
//  * 3rd column-normalize fused with the output write.

namespace {
constexpr int B_ROWS = 16384;
constexpr int K_COLS = 1024;
constexpr float INV_EPS = 20.0f;   // 1/0.05
constexpr float STAB = 1e-9f;
constexpr int NSPREAD = 8;
constexpr int NBLK = 256;
constexpr int RPB = 64;            // rows per block

// workspace float offsets
constexpr int OFF_MV   = 0;        // 256 per-block max slots (no init needed)
constexpr int OFF_BAR  = 256;      // cnt_g[8] @ +64*g, cnt_r @ +512, gen @ +576
constexpr int BAR_FLOATS = 640;    // [256, 896) zeroed by k_smax block 0
constexpr int OFF_P0   = 1024;                     // R0 parts 8x1024
constexpr int OFF_P1   = OFF_P0 + NSPREAD * 1024;  // R1 parts
constexpr int OFF_P2   = OFF_P1 + NSPREAD * 1024;  // R2 parts
constexpr int P_FLOATS = 3 * NSPREAD * 1024;       // 24576
constexpr int P_PER_BLK = P_FLOATS / NBLK;         // 96

// LDS byte offsets (dynamic)
constexpr unsigned L_E   = 0;                   // ushort E[64][1024] = 131072 B
constexpr unsigned L_SCR = 131072;              // float scr[4][1024] = 16384 B
constexpr unsigned L_R   = L_SCR + 16384;       // float r[1024]     = 4096 B
constexpr unsigned L_C   = L_R + 4096;          // float c[64]       = 256 B
constexpr unsigned L_RED = L_C + 256;           // float red[32]     = 128 B
constexpr unsigned LDS_BYTES = L_RED + 128;     // 151936 B (< 160 KiB)
}

__device__ inline unsigned bf16rne(float f) {   // round-to-nearest-even bf16 bits
  unsigned u = __float_as_uint(f);
  return (u + 0x7FFFu + ((u >> 16) & 1u)) >> 16;
}
__device__ inline float bf16tof(unsigned h) { return __uint_as_float(h << 16); }
__device__ inline float bf16lo(unsigned w) { return __uint_as_float(w << 16); }
__device__ inline float bf16hi(unsigned w) { return __uint_as_float(w & 0xFFFF0000u); }

// ---- sampled max + all workspace init (replaces k_zero) ----
__global__ void k_smax(const float4* __restrict__ x, float* __restrict__ ws) {
  __shared__ float sm[4];
  int t = threadIdx.x;  // 256
  int blk = blockIdx.x; // 256
  // zero this block's slice of the spread accumulators
  if (t < P_PER_BLK) ws[OFF_P0 + blk * P_PER_BLK + t] = 0.0f;
  // block 0 zeroes the barrier words (no one else touches them this kernel)
  if (blk == 0) {
    for (int i = t; i < BAR_FLOATS; i += 256) ws[OFF_BAR + i] = 0.0f;
  }
  const float4* xb = x + (size_t)blk * 16 * 1024;   // 16 KiB sample per 256 KiB
  float4 v0 = xb[t], v1 = xb[t + 256], v2 = xb[t + 512], v3 = xb[t + 768];
  float m = fmaxf(fmaxf(fmaxf(v0.x, v0.y), fmaxf(v0.z, v0.w)),
                  fmaxf(fmaxf(v1.x, v1.y), fmaxf(v1.z, v1.w)));
  m = fmaxf(m, fmaxf(fmaxf(fmaxf(v2.x, v2.y), fmaxf(v2.z, v2.w)),
                     fmaxf(fmaxf(v3.x, v3.y), fmaxf(v3.z, v3.w))));
  #pragma unroll
  for (int off = 32; off > 0; off >>= 1) m = fmaxf(m, __shfl_xor(m, off, 64));
  if ((t & 63) == 0) sm[t >> 6] = m;
  __syncthreads();
  if (t == 0) {
    m = fmaxf(fmaxf(sm[0], sm[1]), fmaxf(sm[2], sm[3]));
    ws[OFF_MV + blk] = m;    // private slot: no atomics, no init required
  }
}

// ---- tree grid barrier: 8 groups x 32 + root; RELAXED sc1 polls ----
__device__ inline void gbar(float* ws) {
  __syncthreads();
  if (threadIdx.x == 0) {
    unsigned* cnt_g = (unsigned*)(ws + OFF_BAR + 64 * (blockIdx.x >> 5));
    unsigned* cnt_r = (unsigned*)(ws + OFF_BAR + 512);
    unsigned* gen   = (unsigned*)(ws + OFF_BAR + 576);
    unsigned g = __hip_atomic_load(gen, __ATOMIC_RELAXED, __HIP_MEMORY_SCOPE_AGENT);
    // release-half orders this block's prior atomicAdds before the arrival
    unsigned a = __hip_atomic_fetch_add(cnt_g, 1u, __ATOMIC_ACQ_REL, __HIP_MEMORY_SCOPE_AGENT);
    bool last = false;
    if (a == 31u) {
      unsigned b = __hip_atomic_fetch_add(cnt_r, 1u, __ATOMIC_ACQ_REL, __HIP_MEMORY_SCOPE_AGENT);
      if (b == 7u) {
        // reset ALL counters BEFORE bumping gen; the RELEASE store on gen
        // waits vmcnt(0) so resets are globally complete before gen flips
        #pragma unroll
        for (int i = 0; i < 8; ++i)
          __hip_atomic_store((unsigned*)(ws + OFF_BAR + 64 * i), 0u,
                             __ATOMIC_RELAXED, __HIP_MEMORY_SCOPE_AGENT);
        __hip_atomic_store(cnt_r, 0u, __ATOMIC_RELAXED, __HIP_MEMORY_SCOPE_AGENT);
        __hip_atomic_store(gen, g + 1u, __ATOMIC_RELEASE, __HIP_MEMORY_SCOPE_AGENT);
        last = true;
      }
    }
    if (!last) {
      // RELAXED poll: reads the coherence point without L2 invalidates.
      while (__hip_atomic_load(gen, __ATOMIC_RELAXED, __HIP_MEMORY_SCOPE_AGENT) == g) {
        __builtin_amdgcn_s_sleep(4);
      }
    }
  }
  __syncthreads();
}

__global__ void __launch_bounds__(1024, 4)
k_sink(const float* __restrict__ x, float* __restrict__ out,
       float* __restrict__ ws) {
  extern __shared__ char lds_raw[];
  unsigned short* E = (unsigned short*)(lds_raw + L_E);
  float* scr = (float*)(lds_raw + L_SCR);
  float* r_l = (float*)(lds_raw + L_R);
  float* c_l = (float*)(lds_raw + L_C);
  float* red = (float*)(lds_raw + L_RED);

  const int t = threadIdx.x;       // 1024
  const int blk = blockIdx.x;      // 256
  const int lane = t & 63;
  const int wave = t >> 6;         // 0..15
  const int c0 = t & 255;          // col group: cols 4*c0 .. 4*c0+3
  const int r0 = t >> 8;           // row subgroup 0..3

  const float* xb = x + (size_t)blk * RPB * K_COLS;

  // ---- M: every wave redundantly reduces the 256 per-block max slots ----
  float M;
  {
    float4 q = *(const float4*)(ws + OFF_MV + 4 * lane);  // 64 lanes x 4 = 256
    float m = fmaxf(fmaxf(q.x, q.y), fmaxf(q.z, q.w));
    #pragma unroll
    for (int off = 32; off > 0; off >>= 1) m = fmaxf(m, __shfl_xor(m, off, 64));
    M = m;   // wave-uniform, no syncthreads needed
  }

  // ---- Phase B: E' = bf16(exp((x-M)*20)) -> LDS; R0 partials -> spread ----
  {
    float a0 = 0.f, a1 = 0.f, a2 = 0.f, a3 = 0.f;
    #pragma unroll 4
    for (int i = 0; i < 16; ++i) {
      const int row = 4 * i + r0;
      float4 v = *(const float4*)(xb + (size_t)row * K_COLS + 4 * c0);
      unsigned h0 = bf16rne(__expf((v.x - M) * INV_EPS));
      unsigned h1 = bf16rne(__expf((v.y - M) * INV_EPS));
      unsigned h2 = bf16rne(__expf((v.z - M) * INV_EPS));
      unsigned h3 = bf16rne(__expf((v.w - M) * INV_EPS));
      ushort4 hs;
      hs.x = (unsigned short)h0; hs.y = (unsigned short)h1;
      hs.z = (unsigned short)h2; hs.w = (unsigned short)h3;
      *(ushort4*)(E + row * K_COLS + 4 * c0) = hs;
      // accumulate the QUANTIZED values so all passes agree exactly
      a0 += bf16tof(h0); a1 += bf16tof(h1); a2 += bf16tof(h2); a3 += bf16tof(h3);
    }
    float4 f4; f4.x = a0; f4.y = a1; f4.z = a2; f4.w = a3;
    *(float4*)(scr + r0 * 1024 + 4 * c0) = f4;
    __syncthreads();
    float cs = scr[t] + scr[1024 + t] + scr[2048 + t] + scr[3072 + t];
    atomicAdd(ws + OFF_P0 + (blk & (NSPREAD - 1)) * 1024 + t, cs);
  }
  gbar(ws);

  // ---- fold R0 with sc1 loads (bypass non-coherent L2), S, s, r1, c=1 ----
  float s;
  {
    float R0t = 0.f;
    #pragma unroll
    for (int i = 0; i < NSPREAD; ++i)
      R0t += __hip_atomic_load(ws + OFF_P0 + i * 1024 + t,
                               __ATOMIC_RELAXED, __HIP_MEMORY_SCOPE_AGENT);
    float p = R0t;
    #pragma unroll
    for (int off = 32; off > 0; off >>= 1) p += __shfl_xor(p, off, 64);
    if (lane == 0) red[wave] = p;
    __syncthreads();
    float S = 0.f;
    #pragma unroll
    for (int i = 0; i < 16; ++i) S += red[i];   // same order in every block/thread
    s = 1.0f / (S + STAB);
    r_l[t] = 1.0f / ((s * R0t + STAB) * K_COLS);
    if (t < 64) c_l[t] = 1.0f;
    __syncthreads();
  }

  // ---- column-normalize: c_new[b] from p[b] = sum_k E'[b,k]*r[k] ----
  float rv[16];
  auto load_rv = [&]() {
    #pragma unroll
    for (int j = 0; j < 4; ++j) {
      float4 rr = *(const float4*)(r_l + 256 * j + 4 * lane);
      rv[4 * j + 0] = rr.x; rv[4 * j + 1] = rr.y;
      rv[4 * j + 2] = rr.z; rv[4 * j + 3] = rr.w;
    }
  };

  auto col_pass = [&](bool first) {
    load_rv();
    #pragma unroll
    for (int half = 0; half < 2; ++half) {
      const int row0 = wave + 32 * half;   // wave handles rows {w, w+16, w+32, w+48}
      const int row1 = row0 + 16;
      const unsigned short* e0p = E + row0 * K_COLS + 4 * lane;
      const unsigned short* e1p = E + row1 * K_COLS + 4 * lane;
      float p0 = 0.f, p1 = 0.f;
      #pragma unroll
      for (int j = 0; j < 4; ++j) {
        uint2 u = *(const uint2*)(e0p + 256 * j);
        uint2 v = *(const uint2*)(e1p + 256 * j);
        p0 += bf16lo(u.x) * rv[4*j+0] + bf16hi(u.x) * rv[4*j+1]
            + bf16lo(u.y) * rv[4*j+2] + bf16hi(u.y) * rv[4*j+3];
        p1 += bf16lo(v.x) * rv[4*j+0] + bf16hi(v.x) * rv[4*j+1]
            + bf16lo(v.y) * rv[4*j+2] + bf16hi(v.y) * rv[4*j+3];
      }
      #pragma unroll
      for (int off = 32; off > 0; off >>= 1) {
        p0 += __shfl_xor(p0, off, 64);
        p1 += __shfl_xor(p1, off, 64);
      }
      if (lane == 0) {
        float ci0 = first ? 1.0f : c_l[row0];
        float ci1 = first ? 1.0f : c_l[row1];
        c_l[row0] = ci0 / ((s * ci0 * p0 + STAB) * B_ROWS);
        c_l[row1] = ci1 / ((s * ci1 * p1 + STAB) * B_ROWS);
      }
    }
    __syncthreads();
  };

  // ---- next row-sum partials: A[k] = sum_b E'[b,k]*c[b] -> spread atomics ----
  auto col_acc = [&](float* part) {
    float a0 = 0.f, a1 = 0.f, a2 = 0.f, a3 = 0.f;
    const unsigned short* ep = E + (size_t)(16 * r0) * K_COLS + 4 * c0;
    const float* cp = c_l + 16 * r0;
    #pragma unroll 4
    for (int rr = 0; rr < 16; ++rr) {
      float cv = cp[rr];                       // wave-uniform -> LDS broadcast
      uint2 u = *(const uint2*)(ep + rr * K_COLS);
      a0 += bf16lo(u.x) * cv; a1 += bf16hi(u.x) * cv;
      a2 += bf16lo(u.y) * cv; a3 += bf16hi(u.y) * cv;
    }
    float4 f4; f4.x = a0; f4.y = a1; f4.z = a2; f4.w = a3;
    *(float4*)(scr + r0 * 1024 + 4 * c0) = f4;
    __syncthreads();
    float A = scr[t] + scr[1024 + t] + scr[2048 + t] + scr[3072 + t];
    atomicAdd(part + (blk & (NSPREAD - 1)) * 1024 + t, A);
  };

  // ---- r_new[k] = r[k]/((s*r[k]*A[k]+eps)*K), folding spread parts (sc1) ----
  auto upd_r = [&](float* part) {
    float A = 0.f;
    #pragma unroll
    for (int i = 0; i < NSPREAD; ++i)
      A += __hip_atomic_load(part + i * 1024 + t,
                             __ATOMIC_RELAXED, __HIP_MEMORY_SCOPE_AGENT);
    float rvv = r_l[t];
    r_l[t] = rvv / ((s * rvv * A + STAB) * K_COLS);
    __syncthreads();
  };

  float* P1 = ws + OFF_P1;
  float* P2 = ws + OFF_P2;

  col_pass(true);        // c1
  col_acc(P1);           // R1 parts
  gbar(ws);
  upd_r(P1);             // r2
  col_pass(false);       // c2
  col_acc(P2);           // R2 parts
  gbar(ws);
  upd_r(P2);             // r3

  // ---- fused: c3 + output write. Butterfly leaves p in ALL lanes, so every
  //      lane knows c3; E fragments + rv are already in registers -> write
  //      out[row,k] = s * E' * r3[k] * c3[row] * B directly (regular float4
  //      stores -- round-4's nt stores regressed). ----
  {
    load_rv();           // r3
    #pragma unroll
    for (int half = 0; half < 2; ++half) {
      const int row0 = wave + 32 * half;
      const int row1 = row0 + 16;
      const unsigned short* e0p = E + row0 * K_COLS + 4 * lane;
      const unsigned short* e1p = E + row1 * K_COLS + 4 * lane;
      float q0[16], q1[16];
      #pragma unroll
      for (int j = 0; j < 4; ++j) {
        uint2 u = *(const uint2*)(e0p + 256 * j);
        uint2 v = *(const uint2*)(e1p + 256 * j);
        q0[4*j+0] = bf16lo(u.x) * rv[4*j+0];
        q0[4*j+1] = bf16hi(u.x) * rv[4*j+1];
        q0[4*j+2] = bf16lo(u.y) * rv[4*j+2];
        q0[4*j+3] = bf16hi(u.y) * rv[4*j+3];
        q1[4*j+0] = bf16lo(v.x) * rv[4*j+0];
        q1[4*j+1] = bf16hi(v.x) * rv[4*j+1];
        q1[4*j+2] = bf16lo(v.y) * rv[4*j+2];
        q1[4*j+3] = bf16hi(v.y) * rv[4*j+3];
      }
      float p0 = 0.f, p1 = 0.f;
      #pragma unroll
      for (int i = 0; i < 16; ++i) { p0 += q0[i]; p1 += q1[i]; }
      #pragma unroll
      for (int off = 32; off > 0; off >>= 1) {
        p0 += __shfl_xor(p0, off, 64);
        p1 += __shfl_xor(p1, off, 64);
      }
      float ci0 = c_l[row0];                   // wave-uniform LDS broadcast
      float ci1 = c_l[row1];
      float c0n = ci0 / ((s * ci0 * p0 + STAB) * B_ROWS);
      float c1n = ci1 / ((s * ci1 * p1 + STAB) * B_ROWS);
      float f0 = s * c0n * (float)B_ROWS;
      float f1 = s * c1n * (float)B_ROWS;
      float* o0 = out + (size_t)(blk * RPB + row0) * K_COLS + 4 * lane;
      float* o1 = out + (size_t)(blk * RPB + row1) * K_COLS + 4 * lane;
      #pragma unroll
      for (int j = 0; j < 4; ++j) {
        float4 a, b;
        a.x = q0[4*j+0] * f0; a.y = q0[4*j+1] * f0;
        a.z = q0[4*j+2] * f0; a.w = q0[4*j+3] * f0;
        b.x = q1[4*j+0] * f1; b.y = q1[4*j+1] * f1;
        b.z = q1[4*j+2] * f1; b.w = q1[4*j+3] * f1;
        *(float4*)(o0 + 256 * j) = a;
        *(float4*)(o1 + 256 * j) = b;
      }
    }
  }
}

extern "C" void kernel_launch(void* const* d_in, const int* in_sizes, int n_in,
                              void* d_out, int out_size, void* d_ws, size_t ws_size,
                              hipStream_t stream) {
  const float* x = (const float*)d_in[0];
  float* out = (float*)d_out;
  float* ws = (float*)d_ws;
  (void)in_sizes; (void)n_in; (void)out_size; (void)ws_size;

  static bool attr_set = false;
  if (!attr_set) {
    // opt-in for >64 KiB dynamic LDS (needed for plain launches too)
    hipFuncSetAttribute((const void*)k_sink,
                        hipFuncAttributeMaxDynamicSharedMemorySize,
                        (int)LDS_BYTES);
    attr_set = true;
  }

  k_smax<<<256, 256, 0, stream>>>((const float4*)x, ws);  // max slots + init
  // PLAIN launch (round-6 change): 256 blocks x 148KB LDS = exactly 1
  // block/CU on 256 CUs -> fully co-resident without the cooperative API's
  // per-replay graph-node overhead. Barrier is arrive+spin, order-independent.
  k_sink<<<dim3(NBLK), dim3(1024), LDS_BYTES, stream>>>(x, out, ws);
}